// Round 7
// baseline (502.041 us; speedup 1.0000x reference)
//
#include <hip/hip_runtime.h>

// SelectiveAttnMLA on MI355X (gfx950).
// B=4 S=2048 Hq=16 G=4 D=192 DV=128 BLK=64 NB=32 TOPK=16, out fp32 (8192x2048).
//
// R10: qb-pair fusion. Each WG handles TWO consecutive q-blocks (2u, 2u+1) =
//      128 queries with 4 waves x 32 queries (R9's fused 2-subtile wave core).
//      Halves total WG-iterations (33.8k -> 17.4k) and staged K/V bytes
//      (1.38 -> 0.71 GB) -- the per-iteration L3 round-trip was the bound.
//      Pipeline: K double-buffered (2x24KB), V single buffer + reg detour.
//      Per iter: issue V(nxt) 4 loads + K(nxt) 6 stages FIRST, then
//        W: vmcnt(10)+lgkm0+bar  (K(cur) landed; 10 new ops fly through)
//        QK(cur) -> softmax x2 -> PV(cur from sh_v)
//        G: vmcnt(6)+lgkm0       (V(nxt) regs landed; K(nxt) 6 still flying)
//        H: bar; writeV(nxt)
//      2 barriers/iter; no wait targets a load younger than ~1 iteration.
//      LDS 64KB -> 2 WG/CU; VGPR ~180 uncapped (R7 spill lesson); grid 1024,
//      heavy pairs (u=15, 32 iters) dispatched first for tail balance.

typedef __attribute__((ext_vector_type(8))) _Float16 half8;
typedef __attribute__((ext_vector_type(4))) float f32x4;
typedef __attribute__((ext_vector_type(4))) unsigned int u32x4;

__device__ __forceinline__ half8 cvt8(const float4* p) {
  float4 a = p[0], b = p[1];
  half8 r;
  r[0] = (_Float16)a.x; r[1] = (_Float16)a.y; r[2] = (_Float16)a.z; r[3] = (_Float16)a.w;
  r[4] = (_Float16)b.x; r[5] = (_Float16)b.y; r[6] = (_Float16)b.z; r[7] = (_Float16)b.w;
  return r;
}

__device__ __forceinline__ half8 cvt8s(const float4* p, float s) {
  float4 a = p[0], b = p[1];
  half8 r;
  r[0] = (_Float16)(a.x * s); r[1] = (_Float16)(a.y * s);
  r[2] = (_Float16)(a.z * s); r[3] = (_Float16)(a.w * s);
  r[4] = (_Float16)(b.x * s); r[5] = (_Float16)(b.y * s);
  r[6] = (_Float16)(b.z * s); r[7] = (_Float16)(b.w * s);
  return r;
}

__device__ __forceinline__ void async16(const void* g, void* l) {
  __builtin_amdgcn_global_load_lds(
      (const __attribute__((address_space(1))) void*)g,
      (__attribute__((address_space(3))) void*)l, 16, 0, 0);
}

__device__ __forceinline__ f32x4 vmax4(f32x4 a, f32x4 b) {
  f32x4 r;
  r[0] = fmaxf(a[0], b[0]); r[1] = fmaxf(a[1], b[1]);
  r[2] = fmaxf(a[2], b[2]); r[3] = fmaxf(a[3], b[3]);
  return r;
}

// ---------------- fused K/V fragment prepass (unchanged) ----------------
__global__ __launch_bounds__(256) void kv_prep(const float* __restrict__ k,
                                               const float* __restrict__ v,
                                               _Float16* __restrict__ kf,
                                               _Float16* __restrict__ vf) {
  __shared__ float lb[64 * 196];      // K phase: [64][196]; V phase: [64][132]
  int blk = blockIdx.x;               // (b*16+h)*32 + kb
  int bh = blk >> 5, kb = blk & 31;
  int b = bh >> 4, h = bh & 15;
  int tid = threadIdx.x;

  // ---- K: load 64 rows x 192 f32, coalesced ----
  const float* ksrc = k + ((long)(b * 2048 + kb * 64) * 16 + h) * 192;
#pragma unroll
  for (int it = 0; it < 12; ++it) {
    int idx = it * 256 + tid;         // 3072 float4
    int kk = idx / 48, c4 = idx - kk * 48;
    *(float4*)(&lb[kk * 196 + c4 * 4]) = *(const float4*)(ksrc + (long)kk * 3072 + c4 * 4);
  }
  __syncthreads();
  _Float16* kdst = kf + (long)blk * 12288;
#pragma unroll
  for (int it = 0; it < 6; ++it) {
    int oct = it * 256 + tid;         // 1536 octets
    int frag = oct >> 6, lane = oct & 63;
    int ntile = frag / 6, kc = frag - ntile * 6;
    int lm = lane & 15;
    // permuted row: stored slot (ntile, lm) <- actual key (lm>>2)*16 + ntile*4 + (lm&3)
    int n = ((lm >> 2) << 4) + ntile * 4 + (lm & 3);
    int d = kc * 32 + ((lane >> 4) << 3);
    *(half8*)(kdst + (long)oct * 8) = cvt8((const float4*)(&lb[n * 196 + d]));
  }
  __syncthreads();

  // ---- V: load 64 rows x 128 f32, coalesced; emit transposed frags ----
  const float* vsrc = v + ((long)(b * 2048 + kb * 64) * 16 + h) * 128;
#pragma unroll
  for (int it = 0; it < 8; ++it) {
    int idx = it * 256 + tid;         // 2048 float4
    int kk = idx >> 5, c4 = idx & 31;
    *(float4*)(&lb[kk * 132 + c4 * 4]) = *(const float4*)(vsrc + (long)kk * 2048 + c4 * 4);
  }
  __syncthreads();
  _Float16* vdst = vf + (long)blk * 8192;
#pragma unroll
  for (int it = 0; it < 4; ++it) {
    int oct = it * 256 + tid;         // 1024 octets
    int frag = oct >> 6, lane = oct & 63;
    int n0 = frag >> 1, kc = frag & 1;
    int dv = n0 * 16 + (lane & 15);
    int kbase = kc * 32 + ((lane >> 4) << 3);
    half8 o;
#pragma unroll
    for (int j = 0; j < 8; ++j) o[j] = (_Float16)lb[(kbase + j) * 132 + dv];
    *(half8*)(vdst + (long)oct * 8) = o;
  }
}

// ---------------- main attention: qb-pair per WG, 4 waves x 32 queries ----------------
__global__ __launch_bounds__(256) void attn_main(const float* __restrict__ q,
                                                 const int* __restrict__ idx,
                                                 const _Float16* __restrict__ kf,
                                                 const _Float16* __restrict__ vf,
                                                 float* __restrict__ out) {
  constexpr float SCL = 0.07216878364870322f * 1.4426950408889634f;  // sm_scale*log2e
  int id = (int)blockIdx.x;           // [0,1024)
  int u = 15 - (id >> 6);             // qb pair index, heavy (u=15) first
  int bh = id & 63;
  int h = bh & 15, b = bh >> 4, g = h >> 2;
  int qlo = 2 * u, qhi = 2 * u + 1;
  int tid = threadIdx.x;
  int w = tid >> 6, L = tid & 63;
  int Lm = L & 15, Lq = L >> 4;
  int tile = w >> 1, half = w & 1;    // tile: 0->qb=qlo, 1->qb=qhi
  int myqb = qlo + tile;
  int qoff = half * 32;               // within-tile row offset of this wave
  int t0 = b * 2048 + qlo * 64;       // first token of the pair

  __shared__ __align__(16) char sh_k[2][24576];   // K frag double buffer
  __shared__ __align__(16) char sh_v[16384];      // V frags (16 x 1KB)  = 64KB total

  const char* kfb = (const char*)(kf + (long)((b * 16 + h) * 32) * 12288);
  const _Float16* vfb = vf + (long)((b * 16 + h) * 32) * 8192;

  auto stageK = [&](int kb, char* dst) {
#pragma unroll
    for (int c = 0; c < 6; ++c) {
      int ch = w + c * 4;
      async16(kfb + (long)kb * 24576 + ch * 1024 + L * 16, dst + ch * 1024);
    }
  };
  half8 vreg[4];                      // V detour: regs now, sh_v after barrier H
  auto loadVreg = [&](int kb) {
    const half8* vg = (const half8*)(vfb + (long)kb * 8192);
#pragma unroll
    for (int c = 0; c < 4; ++c) vreg[c] = vg[(w + c * 4) * 64 + L];
  };
  auto writeV = [&]() {
#pragma unroll
    for (int c = 0; c < 4; ++c)
      *(half8*)(sh_v + (w + c * 4) * 1024 + L * 16) = vreg[c];
  };

  // Q as B-operand, two 16-query sub-tiles per wave
  half8 qa[2][6];
#pragma unroll
  for (int j = 0; j < 2; ++j) {
    const float* qrow = q + ((long)(t0 + tile * 64 + qoff + j * 16 + Lm) * 16 + h) * 192;
#pragma unroll
    for (int c = 0; c < 6; ++c) qa[j][c] = cvt8s((const float4*)(qrow + c * 32 + Lq * 8), SCL);
  }

  // selection masks: lane L reads picks of local rows L and L+64 (128 rows total)
  unsigned rm0 = 0, rm1 = 0;
  {
    const int4* ip0 = (const int4*)(idx + ((long)(t0 + L) * 4 + g) * 16);
    const int4* ip1 = (const int4*)(idx + ((long)(t0 + 64 + L) * 4 + g) * 16);
#pragma unroll
    for (int e = 0; e < 4; ++e) {
      int4 i0 = ip0[e], i1 = ip1[e];
      rm0 |= (1u << i0.x) | (1u << i0.y) | (1u << i0.z) | (1u << i0.w);
      rm1 |= (1u << i1.x) | (1u << i1.y) | (1u << i1.z) | (1u << i1.w);
    }
  }
  unsigned bm = rm0 | rm1;
#pragma unroll
  for (int o = 1; o < 64; o <<= 1) bm |= __shfl_xor(bm, o, 64);   // 128-row union
  unsigned mrow[2];
#pragma unroll
  for (int j = 0; j < 2; ++j)
    mrow[j] = __shfl((int)(tile ? rm1 : rm0), qoff + j * 16 + Lm, 64);
  unsigned bmask = bm & ((2u << qhi) - 1);    // bits 0..qhi (qhi=31 wraps all-ones)

  // prologue: block 0 always selected
  loadVreg(0);                         // 4 oldest VM ops
  stageK(0, sh_k[0]);                  // 6 newer
  asm volatile("s_waitcnt vmcnt(0)" ::: "memory");
  writeV();
  asm volatile("s_waitcnt lgkmcnt(0)\n\ts_barrier" ::: "memory");

  f32x4 Oacc[2][8];
#pragma unroll
  for (int j = 0; j < 2; ++j)
#pragma unroll
    for (int n0 = 0; n0 < 8; ++n0) Oacc[j][n0] = (f32x4){0.f, 0.f, 0.f, 0.f};
  float m_i[2] = {-1e30f, -1e30f}, l_i[2] = {0.f, 0.f};

  unsigned rem = bmask;                // bit 0 always set
  int kb = 0, cur = 0;

  for (;;) {
    rem &= rem - 1;
    int nxt = rem ? (int)__builtin_ctz(rem) : -1;

    if (nxt >= 0) {
      loadVreg(nxt);                   // 4 plain loads (older than stages below)
      stageK(nxt, sh_k[cur ^ 1]);      // 6 async16
      // W: K(cur) landed (oldest); the 10 just-issued ops fly through.
      asm volatile("s_waitcnt vmcnt(10) lgkmcnt(0)\n\ts_barrier" ::: "memory");
    } else {
      asm volatile("s_waitcnt vmcnt(0) lgkmcnt(0)\n\ts_barrier" ::: "memory");
    }

    bool active = (kb <= myqb);
    if (active) {
      const half8* lkf = (const half8*)sh_k[cur];
      // fused QK^T: each K fragment feeds both q-sub-tiles
      f32x4 S[2][4];
#pragma unroll
      for (int j = 0; j < 2; ++j)
#pragma unroll
        for (int nt = 0; nt < 4; ++nt) S[j][nt] = (f32x4){0.f, 0.f, 0.f, 0.f};
      __builtin_amdgcn_s_setprio(1);
#pragma unroll
      for (int nt = 0; nt < 4; ++nt)
#pragma unroll
        for (int c = 0; c < 6; ++c) {
          half8 ka = lkf[(nt * 6 + c) * 64 + L];
          S[0][nt] = __builtin_amdgcn_mfma_f32_16x16x32_f16(ka, qa[0][c], S[0][nt], 0, 0, 0);
          S[1][nt] = __builtin_amdgcn_mfma_f32_16x16x32_f16(ka, qa[1][c], S[1][nt], 0, 0, 0);
        }
      __builtin_amdgcn_s_setprio(0);

      // softmax + P-exchange per sub-tile
      half8 pfr[2][2];
#pragma unroll
      for (int j = 0; j < 2; ++j) {
        float p[4][4];
        float msel = ((mrow[j] >> kb) & 1u) ? 1.0f : 0.0f;
        if (kb != myqb) {
          f32x4 t = vmax4(vmax4(S[j][0], S[j][1]), vmax4(S[j][2], S[j][3]));
          float rmax = fmaxf(fmaxf(t[0], t[1]), fmaxf(t[2], t[3]));
          rmax = fmaxf(rmax, __shfl_xor(rmax, 16));
          rmax = fmaxf(rmax, __shfl_xor(rmax, 32));
          if (__any(rmax > m_i[j])) {
            float mn = fmaxf(m_i[j], rmax);
            float av = __builtin_amdgcn_exp2f(m_i[j] - mn);
            m_i[j] = mn;
            l_i[j] *= av;
#pragma unroll
            for (int n0 = 0; n0 < 8; ++n0) Oacc[j][n0] *= av;
          }
          float ps[4];
#pragma unroll
          for (int nt = 0; nt < 4; ++nt) {
            float s0 = 0.f, s1 = 0.f;
#pragma unroll
            for (int i = 0; i < 4; i += 2) {
              float a = __builtin_amdgcn_exp2f(S[j][nt][i] - m_i[j]) * msel;
              float c = __builtin_amdgcn_exp2f(S[j][nt][i + 1] - m_i[j]) * msel;
              p[nt][i] = a; p[nt][i + 1] = c;
              s0 += a; s1 += c;
            }
            ps[nt] = s0 + s1;
          }
          float psum = (ps[0] + ps[1]) + (ps[2] + ps[3]);
          psum += __shfl_xor(psum, 16);
          psum += __shfl_xor(psum, 32);
          l_i[j] += psum;
        } else {
          // diagonal block of this wave's tile: causal+selection per element
          int qr = qoff + j * 16 + Lm;       // within-tile row
          float sc[4][4];
          float rmax = -1e30f;
#pragma unroll
          for (int nt = 0; nt < 4; ++nt)
#pragma unroll
            for (int i = 0; i < 4; ++i) {
              int key = Lq * 16 + nt * 4 + i; // actual key (permuted kf order)
              bool ok = (msel != 0.f) && (key <= qr);
              float v = ok ? S[j][nt][i] : -1e30f;
              sc[nt][i] = v;
              rmax = fmaxf(rmax, v);
            }
          rmax = fmaxf(rmax, __shfl_xor(rmax, 16));
          rmax = fmaxf(rmax, __shfl_xor(rmax, 32));
          float mn = fmaxf(m_i[j], rmax);
          float av = __builtin_amdgcn_exp2f(m_i[j] - mn);
          m_i[j] = mn;
          float ps[4];
#pragma unroll
          for (int nt = 0; nt < 4; ++nt) {
            float s0 = 0.f;
#pragma unroll
            for (int i = 0; i < 4; ++i) {
              float a = __builtin_amdgcn_exp2f(sc[nt][i] - mn);
              p[nt][i] = a;
              s0 += a;
            }
            ps[nt] = s0;
          }
          float psum = (ps[0] + ps[1]) + (ps[2] + ps[3]);
          psum += __shfl_xor(psum, 16);
          psum += __shfl_xor(psum, 32);
          l_i[j] = l_i[j] * av + psum;
#pragma unroll
          for (int n0 = 0; n0 < 8; ++n0) Oacc[j][n0] *= av;
        }

        // pack P to f16 pairs; cross-lane exchange to PV B-fragments
        unsigned w8[8];
#pragma unroll
        for (int nt = 0; nt < 4; ++nt) {
          w8[2 * nt]     = __builtin_bit_cast(unsigned, __builtin_amdgcn_cvt_pkrtz(p[nt][0], p[nt][1]));
          w8[2 * nt + 1] = __builtin_bit_cast(unsigned, __builtin_amdgcn_cvt_pkrtz(p[nt][2], p[nt][3]));
        }
#pragma unroll
        for (int kc = 0; kc < 2; ++kc) {
          int src = ((Lq >> 1) + 2 * kc) * 16 + Lm;
          u32x4 d;
#pragma unroll
          for (int e = 0; e < 4; ++e) {
            unsigned lo = (unsigned)__shfl((int)w8[e], src, 64);
            unsigned hi = (unsigned)__shfl((int)w8[e + 4], src, 64);
            d[e] = (Lq & 1) ? hi : lo;
          }
          pfr[j][kc] = __builtin_bit_cast(half8, d);
        }
      }

      // fused PV: each V fragment feeds both q-sub-tiles
      const half8* lvf = (const half8*)sh_v;
      __builtin_amdgcn_s_setprio(1);
#pragma unroll
      for (int kc = 0; kc < 2; ++kc)
#pragma unroll
        for (int n0 = 0; n0 < 8; ++n0) {
          half8 va = lvf[(n0 * 2 + kc) * 64 + L];
          Oacc[0][n0] = __builtin_amdgcn_mfma_f32_16x16x32_f16(va, pfr[0][kc], Oacc[0][n0], 0, 0, 0);
          Oacc[1][n0] = __builtin_amdgcn_mfma_f32_16x16x32_f16(va, pfr[1][kc], Oacc[1][n0], 0, 0, 0);
        }
      __builtin_amdgcn_s_setprio(0);
    }

    if (nxt < 0) break;
    // G: V(nxt) regs landed (K(nxt)'s 6 keep flying); own sh_v reads retired.
    asm volatile("s_waitcnt vmcnt(6) lgkmcnt(0)" ::: "memory");
    __builtin_amdgcn_s_barrier();      // H: all waves' sh_v reads retired
    writeV();                          // sh_v <- V(nxt); visible via next W
    cur ^= 1;
    kb = nxt;
  }

#pragma unroll
  for (int j = 0; j < 2; ++j) {
    float inv = 1.f / l_i[j];
    float* orow = out + (long)(t0 + tile * 64 + qoff + j * 16 + Lm) * 2048 + h * 128 + Lq * 4;
#pragma unroll
    for (int n0 = 0; n0 < 8; ++n0) {
      f32x4 o = Oacc[j][n0] * inv;
      *(f32x4*)(orow + n0 * 16) = o;
    }
  }
}

extern "C" void kernel_launch(void* const* d_in, const int* in_sizes, int n_in,
                              void* d_out, int out_size, void* d_ws, size_t ws_size,
                              hipStream_t stream) {
  const float* q = (const float*)d_in[0];
  const float* k = (const float*)d_in[1];
  const float* v = (const float*)d_in[2];
  const int* idx = (const int*)d_in[3];
  _Float16* kf = (_Float16*)d_ws;                       // 2048 blk * 12288 f16 = 50.3 MB
  _Float16* vf = kf + (size_t)2048 * 12288;             // 2048 blk * 8192  f16 = 33.6 MB
  float* out = (float*)d_out;
  kv_prep<<<2048, 256, 0, stream>>>(k, v, kf, vf);
  attn_main<<<1024, 256, 0, stream>>>(q, idx, kf, vf, out);
}

// Round 8
// 400.515 us; speedup vs baseline: 1.2535x; 1.2535x over previous
//
#include <hip/hip_runtime.h>

// SelectiveAttnMLA on MI355X (gfx950).
// B=4 S=2048 Hq=16 G=4 D=192 DV=128 BLK=64 NB=32 TOPK=16, out fp32 (8192x2048).
//
// R11: attn_main reverted to R4 exactly (best measured: 170us attn, occupancy
//      tracks perf across R4..R10 -> occupancy-first wins). kv_prep rebuilt
//      with f16 LDS staging: 50KB->25.6KB (3->6 WG/CU), cvt at load time, K
//      fragment phase becomes pure b128 LDS read -> b128 global write with
//      slot-permuted rows (bank-conflict-free); V transpose gather at f16
//      (half bytes, same 4-way). kf/vf layouts unchanged.

typedef __attribute__((ext_vector_type(8))) _Float16 half8;
typedef __attribute__((ext_vector_type(4))) float f32x4;
typedef __attribute__((ext_vector_type(4))) unsigned int u32x4;

__device__ __forceinline__ half8 cvt8s(const float4* p, float s) {
  float4 a = p[0], b = p[1];
  half8 r;
  r[0] = (_Float16)(a.x * s); r[1] = (_Float16)(a.y * s);
  r[2] = (_Float16)(a.z * s); r[3] = (_Float16)(a.w * s);
  r[4] = (_Float16)(b.x * s); r[5] = (_Float16)(b.y * s);
  r[6] = (_Float16)(b.z * s); r[7] = (_Float16)(b.w * s);
  return r;
}

__device__ __forceinline__ void async16(const void* g, void* l) {
  __builtin_amdgcn_global_load_lds(
      (const __attribute__((address_space(1))) void*)g,
      (__attribute__((address_space(3))) void*)l, 16, 0, 0);
}

__device__ __forceinline__ f32x4 vmax4(f32x4 a, f32x4 b) {
  f32x4 r;
  r[0] = fmaxf(a[0], b[0]); r[1] = fmaxf(a[1], b[1]);
  r[2] = fmaxf(a[2], b[2]); r[3] = fmaxf(a[3], b[3]);
  return r;
}

// ---------------- fused K/V fragment prepass, f16 LDS (25.6KB -> 6 WG/CU) ----------------
__global__ __launch_bounds__(256) void kv_prep(const float* __restrict__ k,
                                               const float* __restrict__ v,
                                               _Float16* __restrict__ kf,
                                               _Float16* __restrict__ vf) {
  __shared__ _Float16 lbh[64 * 200];  // K phase: [64 slots][200]; V phase: [64][140]
  int blk = blockIdx.x;               // (b*16+h)*32 + kb
  int bh = blk >> 5, kb = blk & 31;
  int b = bh >> 4, h = bh & 15;
  int tid = threadIdx.x;

  // ---- K: 64 rows x 192 f32, coalesced loads; cvt to f16; permuted slot rows ----
  // stored slot s=(ntile*16+lm) holds actual key a=(lm>>2)*16+ntile*4+(lm&3);
  // inverse: s(kk) = ((kk>>2)&3)*16 + ((kk>>4)<<2) + (kk&3).
  const float* ksrc = k + ((long)(b * 2048 + kb * 64) * 16 + h) * 192;
#pragma unroll
  for (int it = 0; it < 12; ++it) {
    int idx = it * 256 + tid;         // 3072 float4
    int kk = idx / 48, c4 = idx - kk * 48;
    float4 x = *(const float4*)(ksrc + (long)kk * 3072 + c4 * 4);
    int s = ((kk >> 2) & 3) * 16 + ((kk >> 4) << 2) + (kk & 3);
    _Float16* d = &lbh[s * 200 + c4 * 4];
    d[0] = (_Float16)x.x; d[1] = (_Float16)x.y;
    d[2] = (_Float16)x.z; d[3] = (_Float16)x.w;
  }
  __syncthreads();
  _Float16* kdst = kf + (long)blk * 12288;
#pragma unroll
  for (int it = 0; it < 6; ++it) {
    int oct = it * 256 + tid;         // 1536 octets: pure b128 LDS read -> global write
    int frag = oct >> 6, lane = oct & 63;
    int ntile = frag / 6, kc = frag - ntile * 6;
    int s = ntile * 16 + (lane & 15);
    int d = kc * 32 + ((lane >> 4) << 3);
    *(half8*)(kdst + (long)oct * 8) = *(const half8*)(&lbh[s * 200 + d]);
  }
  __syncthreads();

  // ---- V: 64 rows x 128 f32, coalesced; f16 rows stride 140; transposed frags ----
  const float* vsrc = v + ((long)(b * 2048 + kb * 64) * 16 + h) * 128;
#pragma unroll
  for (int it = 0; it < 8; ++it) {
    int idx = it * 256 + tid;         // 2048 float4
    int kk = idx >> 5, c4 = idx & 31;
    float4 x = *(const float4*)(vsrc + (long)kk * 2048 + c4 * 4);
    _Float16* d = &lbh[kk * 140 + c4 * 4];
    d[0] = (_Float16)x.x; d[1] = (_Float16)x.y;
    d[2] = (_Float16)x.z; d[3] = (_Float16)x.w;
  }
  __syncthreads();
  _Float16* vdst = vf + (long)blk * 8192;
#pragma unroll
  for (int it = 0; it < 4; ++it) {
    int oct = it * 256 + tid;         // 1024 octets
    int frag = oct >> 6, lane = oct & 63;
    int n0 = frag >> 1, kc = frag & 1;
    int dv = n0 * 16 + (lane & 15);
    int kbase = kc * 32 + ((lane >> 4) << 3);
    half8 o;
#pragma unroll
    for (int j = 0; j < 8; ++j) o[j] = lbh[(kbase + j) * 140 + dv];
    *(half8*)(vdst + (long)oct * 8) = o;
  }
}

// ---------------- main attention (R4 verbatim: swapped operands, 170us) ----------------
__global__ __launch_bounds__(256) void attn_main(const float* __restrict__ q,
                                                 const int* __restrict__ idx,
                                                 const _Float16* __restrict__ kf,
                                                 const _Float16* __restrict__ vf,
                                                 float* __restrict__ out) {
  constexpr float SCL = 0.07216878364870322f * 1.4426950408889634f;  // sm_scale*log2e
  int id = (int)blockIdx.x;
  int qb = 31 - (id >> 6);            // qb swizzle: CU gets mixed qb, fixed (b,h)
  int h = id & 15, b = (id >> 4) & 3, g = h >> 2;
  int tid = threadIdx.x;
  int w = tid >> 6, L = tid & 63;
  int Lm = L & 15, Lq = L >> 4;
  int m0 = w * 16;
  int t0 = b * 2048 + qb * 64;

  __shared__ __align__(16) char sh_kv[40960];          // 24KB K + 16KB V frags
  __shared__ __align__(16) _Float16 Pbuf[4][16 * 72];  // per-wave [q][key], stride 144B
  __shared__ unsigned un_sh[4];
  char* lk = sh_kv;
  char* lv = sh_kv + 24576;

  // Q as B-operand: col = Lm (query row), k-slots = d
  half8 qa[6];
  const float* qrow = q + ((long)(t0 + m0 + Lm) * 16 + h) * 192;
#pragma unroll
  for (int c = 0; c < 6; ++c) qa[c] = cvt8s((const float4*)(qrow + c * 32 + Lq * 8), SCL);

  // per-lane selection mask for THIS lane's query row (m0+Lm)
  unsigned mrow = 0;
  {
    const int* ip = idx + ((long)(t0 + m0 + Lm) * 4 + g) * 16;
#pragma unroll
    for (int j = 0; j < 16; ++j) mrow |= (1u << ip[j]);
  }
  unsigned un = mrow;
#pragma unroll
  for (int o = 32; o; o >>= 1) un |= __shfl_xor(un, o, 64);
  if (L == 0) un_sh[w] = un;
  __syncthreads();
  unsigned bm = un_sh[0] | un_sh[1] | un_sh[2] | un_sh[3];

  f32x4 Oacc[8];                      // O^T tiles: row = dv (Lq*4+i), col = q (Lm)
#pragma unroll
  for (int n0 = 0; n0 < 8; ++n0) Oacc[n0] = (f32x4){0.f, 0.f, 0.f, 0.f};
  float m_i = -1e30f, l_i = 0.f;      // scalar per lane (row-local)

  const char* kfb = (const char*)(kf + (long)((b * 16 + h) * 32) * 12288);
  const char* vfb = (const char*)(vf + (long)((b * 16 + h) * 32) * 8192);
  _Float16* pw = &Pbuf[w][0];
  const half8* lkf = (const half8*)lk;
  const half8* lvf = (const half8*)lv;

  auto stage = [&](int kb) {
    const char* kg = kfb + (long)kb * 24576;
    const char* vg = vfb + (long)kb * 16384;
#pragma unroll
    for (int c = 0; c < 6; ++c) {
      int ch = w + c * 4;
      async16(kg + ch * 1024 + L * 16, lk + ch * 1024);
    }
#pragma unroll
    for (int c = 0; c < 4; ++c) {
      int ch = w + c * 4;
      async16(vg + ch * 1024 + L * 16, lv + ch * 1024);
    }
  };

  auto compute = [&](int kb, bool lastb) __attribute__((always_inline)) {
    // S^T = K Q^T: lane holds scores of query Lm for actual keys Lq*16 + nt*4 + i
    f32x4 S[4];
#pragma unroll
    for (int nt = 0; nt < 4; ++nt) {
      f32x4 acc = {0.f, 0.f, 0.f, 0.f};
#pragma unroll
      for (int c = 0; c < 6; ++c)
        acc = __builtin_amdgcn_mfma_f32_16x16x32_f16(lkf[(nt * 6 + c) * 64 + L], qa[c], acc, 0, 0, 0);
      S[nt] = acc;
    }

    float p[4][4];
    float msel = ((mrow >> kb) & 1u) ? 1.0f : 0.0f;
    if (!lastb) {
      // selection via per-row 0/1 multiply; inflated row-max from unselected
      // rows is exact (softmax shift-invariance), p*0 kills the values.
      f32x4 t = vmax4(vmax4(S[0], S[1]), vmax4(S[2], S[3]));
      float rmax = fmaxf(fmaxf(t[0], t[1]), fmaxf(t[2], t[3]));
      rmax = fmaxf(rmax, __shfl_xor(rmax, 16));
      rmax = fmaxf(rmax, __shfl_xor(rmax, 32));
      if (__any(rmax > m_i)) {
        float mn = fmaxf(m_i, rmax);
        float av = __builtin_amdgcn_exp2f(m_i - mn);
        m_i = mn;
        l_i *= av;
#pragma unroll
        for (int n0 = 0; n0 < 8; ++n0) Oacc[n0] *= av;
      }
      float ps[4];
#pragma unroll
      for (int nt = 0; nt < 4; ++nt) {
        float s0 = 0.f, s1 = 0.f;
#pragma unroll
        for (int i = 0; i < 4; i += 2) {
          float a = __builtin_amdgcn_exp2f(S[nt][i] - m_i) * msel;
          float c = __builtin_amdgcn_exp2f(S[nt][i + 1] - m_i) * msel;
          p[nt][i] = a; p[nt][i + 1] = c;
          s0 += a; s1 += c;
        }
        ps[nt] = s0 + s1;
      }
      float psum = (ps[0] + ps[1]) + (ps[2] + ps[3]);
      psum += __shfl_xor(psum, 16);
      psum += __shfl_xor(psum, 32);
      l_i += psum;
    } else {
      // diagonal block: full per-element causal+selection masking
      float sc[4][4];
      float rmax = -1e30f;
#pragma unroll
      for (int nt = 0; nt < 4; ++nt)
#pragma unroll
        for (int i = 0; i < 4; ++i) {
          int key = Lq * 16 + nt * 4 + i;   // actual key (permuted kf order)
          bool ok = (msel != 0.f) && (key <= m0 + Lm);
          float v = ok ? S[nt][i] : -1e30f;
          sc[nt][i] = v;
          rmax = fmaxf(rmax, v);
        }
      rmax = fmaxf(rmax, __shfl_xor(rmax, 16));
      rmax = fmaxf(rmax, __shfl_xor(rmax, 32));
      float mn = fmaxf(m_i, rmax);
      float av = __builtin_amdgcn_exp2f(m_i - mn);
      m_i = mn;
      float ps[4];
#pragma unroll
      for (int nt = 0; nt < 4; ++nt) {
        float s0 = 0.f;
#pragma unroll
        for (int i = 0; i < 4; ++i) {
          float a = __builtin_amdgcn_exp2f(sc[nt][i] - mn);
          p[nt][i] = a;
          s0 += a;
        }
        ps[nt] = s0;
      }
      float psum = (ps[0] + ps[1]) + (ps[2] + ps[3]);
      psum += __shfl_xor(psum, 16);
      psum += __shfl_xor(psum, 32);
      l_i = l_i * av + psum;
#pragma unroll
      for (int n0 = 0; n0 < 8; ++n0) Oacc[n0] *= av;
    }

    // P row is lane-contiguous: pack to f16 pairs, 2x b128 store, 2x b128 read.
    asm volatile("s_waitcnt lgkmcnt(0)" ::: "memory");  // WAR vs last iter's reads
    u32x4 w0, w1;
    {
      auto c00 = __builtin_amdgcn_cvt_pkrtz(p[0][0], p[0][1]);
      auto c01 = __builtin_amdgcn_cvt_pkrtz(p[0][2], p[0][3]);
      auto c10 = __builtin_amdgcn_cvt_pkrtz(p[1][0], p[1][1]);
      auto c11 = __builtin_amdgcn_cvt_pkrtz(p[1][2], p[1][3]);
      auto c20 = __builtin_amdgcn_cvt_pkrtz(p[2][0], p[2][1]);
      auto c21 = __builtin_amdgcn_cvt_pkrtz(p[2][2], p[2][3]);
      auto c30 = __builtin_amdgcn_cvt_pkrtz(p[3][0], p[3][1]);
      auto c31 = __builtin_amdgcn_cvt_pkrtz(p[3][2], p[3][3]);
      w0[0] = __builtin_bit_cast(unsigned, c00); w0[1] = __builtin_bit_cast(unsigned, c01);
      w0[2] = __builtin_bit_cast(unsigned, c10); w0[3] = __builtin_bit_cast(unsigned, c11);
      w1[0] = __builtin_bit_cast(unsigned, c20); w1[1] = __builtin_bit_cast(unsigned, c21);
      w1[2] = __builtin_bit_cast(unsigned, c30); w1[3] = __builtin_bit_cast(unsigned, c31);
    }
    *(u32x4*)(pw + Lm * 72 + Lq * 16) = w0;
    *(u32x4*)(pw + Lm * 72 + Lq * 16 + 8) = w1;
    asm volatile("s_waitcnt lgkmcnt(0)" ::: "memory");  // RAW: writes visible

#pragma unroll
    for (int kc = 0; kc < 2; ++kc) {
      half8 pfr = *(const half8*)(pw + Lm * 72 + kc * 32 + Lq * 8);  // B: P^T k-slots
#pragma unroll
      for (int n0 = 0; n0 < 8; ++n0)
        Oacc[n0] = __builtin_amdgcn_mfma_f32_16x16x32_f16(lvf[(n0 * 2 + kc) * 64 + L], pfr, Oacc[n0], 0, 0, 0);
    }
  };

  // kb ascends: block 0 always selected keeps m_i sane before masked blocks.
  for (int kb = 0; kb < qb; ++kb) {
    if (!((bm >> kb) & 1u)) continue;
    stage(kb);
    asm volatile("s_waitcnt vmcnt(0)" ::: "memory");
    __syncthreads();
    if ((un >> kb) & 1u) compute(kb, false);
    __syncthreads();
  }
  if ((bm >> qb) & 1u) {
    stage(qb);
    asm volatile("s_waitcnt vmcnt(0)" ::: "memory");
    __syncthreads();
    if ((un >> qb) & 1u) compute(qb, true);
  }

  float inv = 1.f / l_i;
  float* orow = out + (long)(t0 + m0 + Lm) * 2048 + h * 128 + Lq * 4;
#pragma unroll
  for (int n0 = 0; n0 < 8; ++n0) {
    f32x4 o = Oacc[n0] * inv;
    *(f32x4*)(orow + n0 * 16) = o;
  }
}

extern "C" void kernel_launch(void* const* d_in, const int* in_sizes, int n_in,
                              void* d_out, int out_size, void* d_ws, size_t ws_size,
                              hipStream_t stream) {
  const float* q = (const float*)d_in[0];
  const float* k = (const float*)d_in[1];
  const float* v = (const float*)d_in[2];
  const int* idx = (const int*)d_in[3];
  _Float16* kf = (_Float16*)d_ws;                       // 2048 blk * 12288 f16 = 50.3 MB
  _Float16* vf = kf + (size_t)2048 * 12288;             // 2048 blk * 8192  f16 = 33.6 MB
  float* out = (float*)d_out;
  kv_prep<<<2048, 256, 0, stream>>>(k, v, kf, vf);
  attn_main<<<2048, 256, 0, stream>>>(q, idx, kf, vf, out);
}